// Round 1
// baseline (870.165 us; speedup 1.0000x reference)
//
#include <hip/hip_runtime.h>

#define DEVFN __device__ __forceinline__

typedef float  floatx4 __attribute__((ext_vector_type(4)));
typedef __bf16 bf16x8  __attribute__((ext_vector_type(8)));

#define MFMA16(a, b, c) __builtin_amdgcn_mfma_f32_16x16x32_bf16((a), (b), (c), 0, 0, 0)

DEVFN unsigned short f2bf(float f) {
  union { float f; unsigned u; } v; v.f = f;
  unsigned r = v.u + 0x7FFFu + ((v.u >> 16) & 1u);
  return (unsigned short)(r >> 16);
}
DEVFN float bf2f(unsigned short b) {
  union { unsigned u; float f; } v; v.u = ((unsigned)b) << 16;
  return v.f;
}
DEVFN void async16(void* lds, const void* g) {
  __builtin_amdgcn_global_load_lds(
      (const __attribute__((address_space(1))) unsigned int*)g,
      (__attribute__((address_space(3))) unsigned int*)lds, 16, 0, 0);
}
DEVFN bf16x8 ld8(const unsigned short* p) { return *(const bf16x8*)p; }

// ---------------------------------------------------------------------------
// split fp32 -> bf16 hi (+ optional lo residual)
// ---------------------------------------------------------------------------
__global__ __launch_bounds__(256) void split_kernel(
    const float4* __restrict__ x, ushort4* __restrict__ hi,
    ushort4* __restrict__ lo, int n4) {
  int i = blockIdx.x * 256 + threadIdx.x;
  if (i >= n4) return;
  float4 v = x[i];
  ushort4 h;
  h.x = f2bf(v.x); h.y = f2bf(v.y); h.z = f2bf(v.z); h.w = f2bf(v.w);
  hi[i] = h;
  if (lo) {
    ushort4 l;
    l.x = f2bf(v.x - bf2f(h.x)); l.y = f2bf(v.y - bf2f(h.y));
    l.z = f2bf(v.z - bf2f(h.z)); l.w = f2bf(v.w - bf2f(h.w));
    lo[i] = l;
  }
}

// ---------------------------------------------------------------------------
// RoPE tables in fp64 (T=2048, d2=64)
// ---------------------------------------------------------------------------
__global__ __launch_bounds__(256) void rope_tables(float* __restrict__ cosT,
                                                   float* __restrict__ sinT) {
  int i = blockIdx.x * 256 + threadIdx.x;
  if (i >= 2048 * 64) return;
  int t = i >> 6, d = i & 63;
  double theta = exp(-((double)(2 * d) / 128.0) * log(10000.0));
  double ang = (double)t * theta;
  cosT[i] = (float)cos(ang);
  sinT[i] = (float)sin(ang);
}

// ---------------------------------------------------------------------------
// GEMM C = A @ B^T, M=4096, N=2048, K=2048, up to 3 accumulate passes.
// 128x128 tile, BK=32, 4 waves x (32 rows x 128 cols).
// LDS granule layout: chunk t (16 rows) holds granule(g=quad,k-half, r=row)
// at (t*512 + lane*8) ushorts so ds_read_b128 is lane-linear (conflict-free)
// and global_load_lds lane order matches (lds dest = base + lane*16B).
// epi: 0 = fp32 store to outF[row*2048+col]
//      1 = RoPE + sqk*escale + split -> oHi/oLo at [B,NH,T,HD]
//      2 = bf16 store -> oHi at [B,NH,T,HD]
// ---------------------------------------------------------------------------
__global__ __launch_bounds__(256, 2) void gemm_bt(
    const unsigned short* __restrict__ A0, const unsigned short* __restrict__ B0,
    const unsigned short* __restrict__ A1, const unsigned short* __restrict__ B1,
    const unsigned short* __restrict__ A2, const unsigned short* __restrict__ B2,
    int npass, int epi,
    const float* __restrict__ cosT, const float* __restrict__ sinT,
    const float* __restrict__ sqk, float escale,
    unsigned short* __restrict__ oHi, unsigned short* __restrict__ oLo,
    float* __restrict__ outF) {
  constexpr int Kd = 2048;
  constexpr int Nd = 2048;
  const int n0 = blockIdx.x * 128, m0 = blockIdx.y * 128;
  const int tid = threadIdx.x, w = tid >> 6, lane = tid & 63;
  const int quad = lane >> 4, l16 = lane & 15;

  __shared__ __align__(16) unsigned short As[4096];  // 8 KB
  __shared__ __align__(16) unsigned short Bs[4096];  // 8 KB

  floatx4 acc[2][8];
#pragma unroll
  for (int i = 0; i < 2; i++)
#pragma unroll
    for (int j = 0; j < 8; j++) acc[i][j] = (floatx4){0.f, 0.f, 0.f, 0.f};

  const int t0 = 2 * w, t1 = 2 * w + 1;

  for (int p = 0; p < npass; ++p) {
    const unsigned short* Ap = (p == 0) ? A0 : ((p == 1) ? A1 : A2);
    const unsigned short* Bp = (p == 0) ? B0 : ((p == 1) ? B1 : B2);
    for (int k0 = 0; k0 < Kd; k0 += 32) {
      __syncthreads();
      async16(&As[t0 * 512], Ap + (size_t)(m0 + t0 * 16 + l16) * Kd + k0 + quad * 8);
      async16(&As[t1 * 512], Ap + (size_t)(m0 + t1 * 16 + l16) * Kd + k0 + quad * 8);
      async16(&Bs[t0 * 512], Bp + (size_t)(n0 + t0 * 16 + l16) * Kd + k0 + quad * 8);
      async16(&Bs[t1 * 512], Bp + (size_t)(n0 + t1 * 16 + l16) * Kd + k0 + quad * 8);
      __syncthreads();
      bf16x8 a0 = ld8(&As[t0 * 512 + lane * 8]);
      bf16x8 a1 = ld8(&As[t1 * 512 + lane * 8]);
#pragma unroll
      for (int j = 0; j < 8; j++) {
        bf16x8 bb = ld8(&Bs[j * 512 + lane * 8]);
        acc[0][j] = MFMA16(a0, bb, acc[0][j]);
        acc[1][j] = MFMA16(a1, bb, acc[1][j]);
      }
    }
  }

  if (epi == 0) {
#pragma unroll
    for (int i = 0; i < 2; i++) {
      int rbase = m0 + (2 * w + i) * 16 + quad * 4;
#pragma unroll
      for (int j = 0; j < 8; j++) {
        int col = n0 + j * 16 + l16;
#pragma unroll
        for (int r = 0; r < 4; r++)
          outF[(size_t)(rbase + r) * Nd + col] = acc[i][j][r];
      }
    }
  } else if (epi == 2) {
    int h = n0 >> 7;
#pragma unroll
    for (int i = 0; i < 2; i++) {
      int rbase = m0 + (2 * w + i) * 16 + quad * 4;
#pragma unroll
      for (int r = 0; r < 4; r++) {
        int row = rbase + r;
        int bb = row >> 11, t = row & 2047;
        size_t base = (((size_t)(bb * 16 + h)) * 2048 + (size_t)t) * 128;
#pragma unroll
        for (int j = 0; j < 8; j++)
          oHi[base + j * 16 + l16] = f2bf(acc[i][j][r]);
      }
    }
  } else {  // epi == 1: RoPE + scale + split
    int h = n0 >> 7;
#pragma unroll
    for (int i = 0; i < 2; i++) {
      int rbase = m0 + (2 * w + i) * 16 + quad * 4;
#pragma unroll
      for (int r = 0; r < 4; r++) {
        int row = rbase + r;
        int bb = row >> 11, t = row & 2047;
        size_t base = (((size_t)(bb * 16 + h)) * 2048 + (size_t)t) * 128;
#pragma unroll
        for (int j = 0; j < 4; j++) {
          int d = j * 16 + l16;  // 0..63
          float xr = acc[i][j][r], xi = acc[i][j + 4][r];
          float c = cosT[t * 64 + d], s = sinT[t * 64 + d];
          float o1 = (xr * c - xi * s) * (sqk[h * 128 + d] * escale);
          float o2 = (xr * s + xi * c) * (sqk[h * 128 + d + 64] * escale);
          unsigned short h1 = f2bf(o1);
          unsigned short h2 = f2bf(o2);
          oHi[base + d] = h1;
          oLo[base + d] = f2bf(o1 - bf2f(h1));
          oHi[base + d + 64] = h2;
          oLo[base + d + 64] = f2bf(o2 - bf2f(h2));
        }
      }
    }
  }
}

// ---------------------------------------------------------------------------
// transpose V: [BH][T][HD] -> [BH][HD][T] (bf16)
// ---------------------------------------------------------------------------
__global__ __launch_bounds__(256) void transpose_v(
    const unsigned short* __restrict__ v, unsigned short* __restrict__ vt) {
  __shared__ unsigned short tile[32][33];
  int t0 = blockIdx.x * 32, d0 = blockIdx.y * 32, bh = blockIdx.z;
  int tx = threadIdx.x & 31, ty = threadIdx.x >> 5;
  for (int r = ty; r < 32; r += 8)
    tile[r][tx] = v[((size_t)bh * 2048 + t0 + r) * 128 + d0 + tx];
  __syncthreads();
  for (int r = ty; r < 32; r += 8)
    vt[((size_t)bh * 128 + d0 + r) * 2048 + t0 + tx] = tile[tx][r];
}

// ---------------------------------------------------------------------------
// flash attention: block = (q-tile of 128 rows, bh). 4 waves x 32 rows.
// K-tiles of 64, QK^T 3-pass split-bf16, online softmax fp32, PV bf16.
// q,k stored post-RoPE as hi/lo bf16 [BH][T][128]; v transposed [BH][128][T].
// out: bf16 at [B,T,NH*HD] (rows b*T+t, col h*128+d).
// ---------------------------------------------------------------------------
__global__ __launch_bounds__(256, 2) void flash_attn(
    const unsigned short* __restrict__ qhi, const unsigned short* __restrict__ qlo,
    const unsigned short* __restrict__ khi, const unsigned short* __restrict__ klo,
    const unsigned short* __restrict__ vtp, unsigned short* __restrict__ aout) {
  constexpr int T = 2048, HD = 128;
  const int qt = blockIdx.x, bh = blockIdx.y;
  const int q0 = qt * 128;
  const int tid = threadIdx.x, w = tid >> 6, lane = tid & 63;
  const int quad = lane >> 4, l16 = lane & 15;

  __shared__ __align__(16) unsigned short Khi[8192];   // 64 x 128, granule layout
  __shared__ __align__(16) unsigned short Klo[8192];
  __shared__ __align__(16) unsigned short Vt[8192];    // 128 x 64, granule layout
  __shared__ __align__(16) unsigned short Pb[4][16 * 72];  // per-wave, padded

  const size_t qkbase = (size_t)bh * T * HD;

  bf16x8 qh[2][4], ql[2][4];
#pragma unroll
  for (int i = 0; i < 2; i++)
#pragma unroll
    for (int s = 0; s < 4; s++) {
      size_t off = qkbase + (size_t)(q0 + w * 32 + i * 16 + l16) * HD + s * 32 + quad * 8;
      qh[i][s] = *(const bf16x8*)(qhi + off);
      ql[i][s] = *(const bf16x8*)(qlo + off);
    }

  floatx4 o[2][8];
#pragma unroll
  for (int i = 0; i < 2; i++)
#pragma unroll
    for (int dt = 0; dt < 8; dt++) o[i][dt] = (floatx4){0.f, 0.f, 0.f, 0.f};
  float mrow[2][4], lrow[2][4];
#pragma unroll
  for (int i = 0; i < 2; i++)
#pragma unroll
    for (int r = 0; r < 4; r++) { mrow[i][r] = -3e38f; lrow[i][r] = 0.f; }

  const int ntiles = q0 / 64 + 2;
  for (int kt = 0; kt < ntiles; ++kt) {
    const int s0 = kt * 64;
    __syncthreads();
    for (int c = w; c < 16; c += 4) {
      int tt = c >> 2, ss = c & 3;
      size_t go = qkbase + (size_t)(s0 + tt * 16 + l16) * HD + ss * 32 + quad * 8;
      async16(&Khi[c * 512], khi + go);
      async16(&Klo[c * 512], klo + go);
      int dt = c >> 1, vs = c & 1;
      size_t vo = (size_t)bh * HD * T + (size_t)(dt * 16 + l16) * T + s0 + vs * 32 + quad * 8;
      async16(&Vt[c * 512], vtp + vo);
    }
    __syncthreads();

    floatx4 S[2][4];
#pragma unroll
    for (int i = 0; i < 2; i++)
#pragma unroll
      for (int j = 0; j < 4; j++) S[i][j] = (floatx4){0.f, 0.f, 0.f, 0.f};

#pragma unroll
    for (int s = 0; s < 4; s++) {
#pragma unroll
      for (int j = 0; j < 4; j++) {
        bf16x8 kh = ld8(&Khi[(j * 4 + s) * 512 + lane * 8]);
        bf16x8 kl = ld8(&Klo[(j * 4 + s) * 512 + lane * 8]);
        S[0][j] = MFMA16(qh[0][s], kh, S[0][j]);
        S[1][j] = MFMA16(qh[1][s], kh, S[1][j]);
        S[0][j] = MFMA16(ql[0][s], kh, S[0][j]);
        S[1][j] = MFMA16(ql[1][s], kh, S[1][j]);
        S[0][j] = MFMA16(qh[0][s], kl, S[0][j]);
        S[1][j] = MFMA16(qh[1][s], kl, S[1][j]);
      }
    }

    if (s0 + 63 > q0) {  // causal mask (only near-diagonal tiles)
#pragma unroll
      for (int i = 0; i < 2; i++) {
        int rb = q0 + w * 32 + i * 16 + quad * 4;
#pragma unroll
        for (int j = 0; j < 4; j++) {
          int cg = s0 + j * 16 + l16;
#pragma unroll
          for (int r = 0; r < 4; r++)
            if (cg > rb + r) S[i][j][r] = -3e38f;
        }
      }
    }

    bf16x8 pf[2][2];
#pragma unroll
    for (int i = 0; i < 2; i++) {
#pragma unroll
      for (int r = 0; r < 4; r++) {
        float mx = fmaxf(fmaxf(S[i][0][r], S[i][1][r]), fmaxf(S[i][2][r], S[i][3][r]));
#pragma unroll
        for (int d = 1; d < 16; d <<= 1) mx = fmaxf(mx, __shfl_xor(mx, d, 64));
        float mnew = fmaxf(mrow[i][r], mx);
        float al = __expf(mrow[i][r] - mnew);
        mrow[i][r] = mnew;
        float sum = 0.f;
#pragma unroll
        for (int j = 0; j < 4; j++) {
          float p = __expf(S[i][j][r] - mnew);
          S[i][j][r] = p;
          sum += p;
        }
#pragma unroll
        for (int d = 1; d < 16; d <<= 1) sum += __shfl_xor(sum, d, 64);
        lrow[i][r] = lrow[i][r] * al + sum;
#pragma unroll
        for (int dt = 0; dt < 8; dt++) o[i][dt][r] *= al;
      }
      // P -> LDS (A-fragment transform); per-wave buffer, DS ops in-order per wave
#pragma unroll
      for (int r = 0; r < 4; r++)
#pragma unroll
        for (int j = 0; j < 4; j++)
          Pb[w][(quad * 4 + r) * 72 + j * 16 + l16] = f2bf(S[i][j][r]);
      pf[i][0] = ld8(&Pb[w][l16 * 72 + quad * 8]);
      pf[i][1] = ld8(&Pb[w][l16 * 72 + 32 + quad * 8]);
    }

#pragma unroll
    for (int dt = 0; dt < 8; dt++) {
#pragma unroll
      for (int s = 0; s < 2; s++) {
        bf16x8 vf = ld8(&Vt[(dt * 2 + s) * 512 + lane * 8]);
        o[0][dt] = MFMA16(pf[0][s], vf, o[0][dt]);
        o[1][dt] = MFMA16(pf[1][s], vf, o[1][dt]);
      }
    }
  }

  const int b = bh >> 4, h = bh & 15;
#pragma unroll
  for (int i = 0; i < 2; i++) {
#pragma unroll
    for (int r = 0; r < 4; r++) {
      int trow = q0 + w * 32 + i * 16 + quad * 4 + r;
      float linv = 1.0f / lrow[i][r];
      size_t base = ((size_t)(b * T + trow)) * 2048 + h * 128;
#pragma unroll
      for (int dt = 0; dt < 8; dt++)
        aout[base + dt * 16 + l16] = f2bf(o[i][dt][r] * linv);
    }
  }
}

// ---------------------------------------------------------------------------
// per-row L2 normalize: out = y / max(||y||, 1e-12)
// ---------------------------------------------------------------------------
__global__ __launch_bounds__(256) void rownorm(const float* __restrict__ y,
                                               float* __restrict__ out) {
  int row = blockIdx.x;
  const float4* yr = (const float4*)(y + (size_t)row * 2048);
  float4* od = (float4*)(out + (size_t)row * 2048);
  int t = threadIdx.x;
  float4 v0 = yr[t], v1 = yr[t + 256];
  float ss = v0.x * v0.x + v0.y * v0.y + v0.z * v0.z + v0.w * v0.w +
             v1.x * v1.x + v1.y * v1.y + v1.z * v1.z + v1.w * v1.w;
#pragma unroll
  for (int d = 1; d < 64; d <<= 1) ss += __shfl_xor(ss, d, 64);
  __shared__ float red[4];
  if ((t & 63) == 0) red[t >> 6] = ss;
  __syncthreads();
  float tot = red[0] + red[1] + red[2] + red[3];
  float inv = 1.0f / fmaxf(sqrtf(tot), 1e-12f);
  v0.x *= inv; v0.y *= inv; v0.z *= inv; v0.w *= inv;
  v1.x *= inv; v1.y *= inv; v1.z *= inv; v1.w *= inv;
  od[t] = v0;
  od[t + 256] = v1;
}

// ---------------------------------------------------------------------------
extern "C" void kernel_launch(void* const* d_in, const int* in_sizes, int n_in,
                              void* d_out, int out_size, void* d_ws, size_t ws_size,
                              hipStream_t stream) {
  (void)in_sizes; (void)n_in; (void)out_size; (void)ws_size;
  const float* x   = (const float*)d_in[0];
  const float* Wq  = (const float*)d_in[1];
  const float* Wk  = (const float*)d_in[2];
  const float* Wv  = (const float*)d_in[3];
  const float* Wo  = (const float*)d_in[4];
  const float* sqk = (const float*)d_in[5];
  char* ws = (char*)d_ws;

  constexpr size_t NX = 8388608;   // 2*2048*2048
  constexpr size_t NW = 4194304;   // 2048*2048
  constexpr size_t SZX = NX * 2;   // bf16 bytes
  constexpr size_t SZW = NW * 2;

  size_t o_xhi  = 0;
  size_t o_xlo  = o_xhi + SZX;
  size_t o_wqhi = o_xlo + SZX;
  size_t o_wqlo = o_wqhi + SZW;
  size_t o_wkhi = o_wqlo + SZW;
  size_t o_wklo = o_wkhi + SZW;
  size_t o_wvhi = o_wklo + SZW;
  size_t o_wohi = o_wvhi + SZW;
  size_t o_qhi  = o_wohi + SZW;
  size_t o_qlo  = o_qhi + SZX;
  size_t o_khi  = o_qlo + SZX;
  size_t o_klo  = o_khi + SZX;
  size_t o_v    = o_klo + SZX;
  size_t o_vt   = o_v + SZX;
  size_t o_cos  = o_vt + SZX;
  size_t o_sin  = o_cos + 2048 * 64 * 4;
  // aliases (lifetimes disjoint):
  size_t o_y    = o_xhi;   // fp32 y over x_hi+x_lo (x dead after projections)
  size_t o_aout = o_wqhi;  // attn-out over wq_hi+wq_lo (dead after Q proj)

  unsigned short* xhi  = (unsigned short*)(ws + o_xhi);
  unsigned short* xlo  = (unsigned short*)(ws + o_xlo);
  unsigned short* wqhi = (unsigned short*)(ws + o_wqhi);
  unsigned short* wqlo = (unsigned short*)(ws + o_wqlo);
  unsigned short* wkhi = (unsigned short*)(ws + o_wkhi);
  unsigned short* wklo = (unsigned short*)(ws + o_wklo);
  unsigned short* wvhi = (unsigned short*)(ws + o_wvhi);
  unsigned short* wohi = (unsigned short*)(ws + o_wohi);
  unsigned short* qhi  = (unsigned short*)(ws + o_qhi);
  unsigned short* qlo  = (unsigned short*)(ws + o_qlo);
  unsigned short* khi  = (unsigned short*)(ws + o_khi);
  unsigned short* klo  = (unsigned short*)(ws + o_klo);
  unsigned short* v    = (unsigned short*)(ws + o_v);
  unsigned short* vt   = (unsigned short*)(ws + o_vt);
  float* cosT = (float*)(ws + o_cos);
  float* sinT = (float*)(ws + o_sin);
  float* y    = (float*)(ws + o_y);
  unsigned short* aout = (unsigned short*)(ws + o_aout);

  // prep
  split_kernel<<<(int)(NX / 4 / 256), 256, 0, stream>>>((const float4*)x, (ushort4*)xhi, (ushort4*)xlo, (int)(NX / 4));
  split_kernel<<<(int)(NW / 4 / 256), 256, 0, stream>>>((const float4*)Wq, (ushort4*)wqhi, (ushort4*)wqlo, (int)(NW / 4));
  split_kernel<<<(int)(NW / 4 / 256), 256, 0, stream>>>((const float4*)Wk, (ushort4*)wkhi, (ushort4*)wklo, (int)(NW / 4));
  split_kernel<<<(int)(NW / 4 / 256), 256, 0, stream>>>((const float4*)Wv, (ushort4*)wvhi, (ushort4*)nullptr, (int)(NW / 4));
  split_kernel<<<(int)(NW / 4 / 256), 256, 0, stream>>>((const float4*)Wo, (ushort4*)wohi, (ushort4*)nullptr, (int)(NW / 4));
  rope_tables<<<512, 256, 0, stream>>>(cosT, sinT);

  dim3 gg(16, 32);
  const float escQ = 512.0f;         // sqrt(2048)*sqrt(128)
  const float escK = 45.254834f;     // sqrt(2048)

  // Q = rope(x@Wq^T)*sqk*RS*sqrt(HD), split-stored  (3-pass split bf16)
  gemm_bt<<<gg, 256, 0, stream>>>(xhi, wqhi, xlo, wqhi, xhi, wqlo, 3, 1,
                                  cosT, sinT, sqk, escQ, qhi, qlo, nullptr);
  // K = rope(x@Wk^T)*sqk*RS, split-stored
  gemm_bt<<<gg, 256, 0, stream>>>(xhi, wkhi, xlo, wkhi, xhi, wklo, 3, 1,
                                  cosT, sinT, sqk, escK, khi, klo, nullptr);
  // V = x@Wv^T (plain bf16)
  gemm_bt<<<gg, 256, 0, stream>>>(xhi, wvhi, nullptr, nullptr, nullptr, nullptr, 1, 2,
                                  nullptr, nullptr, nullptr, 0.f, v, nullptr, nullptr);
  transpose_v<<<dim3(64, 4, 32), 256, 0, stream>>>(v, vt);

  flash_attn<<<dim3(16, 32), 256, 0, stream>>>(qhi, qlo, khi, klo, vt, aout);

  // y = aout @ Wo^T (fp32 out)
  gemm_bt<<<gg, 256, 0, stream>>>(aout, wohi, nullptr, nullptr, nullptr, nullptr, 1, 0,
                                  nullptr, nullptr, nullptr, 0.f, nullptr, nullptr, y);
  rownorm<<<4096, 256, 0, stream>>>(y, (float*)d_out);
}

// Round 2
// 805.450 us; speedup vs baseline: 1.0803x; 1.0803x over previous
//
#include <hip/hip_runtime.h>

#define DEVFN __device__ __forceinline__

typedef float  floatx4 __attribute__((ext_vector_type(4)));
typedef __bf16 bf16x8  __attribute__((ext_vector_type(8)));

#define MFMA16(a, b, c) __builtin_amdgcn_mfma_f32_16x16x32_bf16((a), (b), (c), 0, 0, 0)

DEVFN unsigned short f2bf(float f) {
  union { float f; unsigned u; } v; v.f = f;
  unsigned r = v.u + 0x7FFFu + ((v.u >> 16) & 1u);
  return (unsigned short)(r >> 16);
}
DEVFN float bf2f(unsigned short b) {
  union { unsigned u; float f; } v; v.u = ((unsigned)b) << 16;
  return v.f;
}
DEVFN void async16(void* lds, const void* g) {
  __builtin_amdgcn_global_load_lds(
      (const __attribute__((address_space(1))) unsigned int*)g,
      (__attribute__((address_space(3))) unsigned int*)lds, 16, 0, 0);
}
DEVFN bf16x8 ld8(const unsigned short* p) { return *(const bf16x8*)p; }

// ---------------------------------------------------------------------------
// split fp32 -> bf16 hi (+ optional lo residual)
// ---------------------------------------------------------------------------
__global__ __launch_bounds__(256) void split_kernel(
    const float4* __restrict__ x, ushort4* __restrict__ hi,
    ushort4* __restrict__ lo, int n4) {
  int i = blockIdx.x * 256 + threadIdx.x;
  if (i >= n4) return;
  float4 v = x[i];
  ushort4 h;
  h.x = f2bf(v.x); h.y = f2bf(v.y); h.z = f2bf(v.z); h.w = f2bf(v.w);
  hi[i] = h;
  if (lo) {
    ushort4 l;
    l.x = f2bf(v.x - bf2f(h.x)); l.y = f2bf(v.y - bf2f(h.y));
    l.z = f2bf(v.z - bf2f(h.z)); l.w = f2bf(v.w - bf2f(h.w));
    lo[i] = l;
  }
}

// ---------------------------------------------------------------------------
// RoPE tables in fp64 (T=2048, d2=64)
// ---------------------------------------------------------------------------
__global__ __launch_bounds__(256) void rope_tables(float* __restrict__ cosT,
                                                   float* __restrict__ sinT) {
  int i = blockIdx.x * 256 + threadIdx.x;
  if (i >= 2048 * 64) return;
  int t = i >> 6, d = i & 63;
  double theta = exp(-((double)(2 * d) / 128.0) * log(10000.0));
  double ang = (double)t * theta;
  cosT[i] = (float)cos(ang);
  sinT[i] = (float)sin(ang);
}

// ---------------------------------------------------------------------------
// Fused QKV projection. C_q = x@Wq^T (3-pass split), C_k = x@Wk^T (3-pass),
// C_v = x@Wv^T (hi only). 128x128 tile per block, BK=32.
// Per k-step: 7 LDS buffers (56 KB), 112 MFMA per wave -> barrier cost
// amortized 7x vs separate kernels; x-tiles loaded once for all three.
// Epilogue: RoPE+sqk*escale+split for Q,K; plain bf16 for V. All stored
// at [B,NH,T,HD].
// LDS granule layout: chunk t (16 rows) at (t*512 + lane*8) ushorts so both
// global_load_lds (lane-linear dest) and ds_read_b128 are conflict-free.
// ---------------------------------------------------------------------------
__global__ __launch_bounds__(256, 2) void gemm_qkv(
    const unsigned short* __restrict__ xhi, const unsigned short* __restrict__ xlo,
    const unsigned short* __restrict__ wqh, const unsigned short* __restrict__ wql,
    const unsigned short* __restrict__ wkh, const unsigned short* __restrict__ wkl,
    const unsigned short* __restrict__ wvh,
    const float* __restrict__ cosT, const float* __restrict__ sinT,
    const float* __restrict__ sqk,
    unsigned short* __restrict__ qhi, unsigned short* __restrict__ qlo,
    unsigned short* __restrict__ khi, unsigned short* __restrict__ klo,
    unsigned short* __restrict__ vout) {
  constexpr int Kd = 2048;
  const int n0 = blockIdx.x * 128, m0 = blockIdx.y * 128;
  const int tid = threadIdx.x, w = tid >> 6, lane = tid & 63;
  const int quad = lane >> 4, l16 = lane & 15;

  __shared__ __align__(16) unsigned short Xh[4096], Xl[4096];
  __shared__ __align__(16) unsigned short Qh[4096], Ql[4096];
  __shared__ __align__(16) unsigned short Kh[4096], Kl[4096];
  __shared__ __align__(16) unsigned short Vh[4096];

  floatx4 accQ[2][8], accK[2][8], accV[2][8];
#pragma unroll
  for (int i = 0; i < 2; i++)
#pragma unroll
    for (int j = 0; j < 8; j++) {
      accQ[i][j] = (floatx4){0.f, 0.f, 0.f, 0.f};
      accK[i][j] = (floatx4){0.f, 0.f, 0.f, 0.f};
      accV[i][j] = (floatx4){0.f, 0.f, 0.f, 0.f};
    }

  const int t0 = 2 * w, t1 = 2 * w + 1;
  const size_t xo0 = (size_t)(m0 + t0 * 16 + l16) * Kd + quad * 8;
  const size_t xo1 = (size_t)(m0 + t1 * 16 + l16) * Kd + quad * 8;
  const size_t wo0 = (size_t)(n0 + t0 * 16 + l16) * Kd + quad * 8;
  const size_t wo1 = (size_t)(n0 + t1 * 16 + l16) * Kd + quad * 8;

  for (int k0 = 0; k0 < Kd; k0 += 32) {
    __syncthreads();
    async16(&Xh[t0 * 512], xhi + xo0 + k0);
    async16(&Xh[t1 * 512], xhi + xo1 + k0);
    async16(&Xl[t0 * 512], xlo + xo0 + k0);
    async16(&Xl[t1 * 512], xlo + xo1 + k0);
    async16(&Qh[t0 * 512], wqh + wo0 + k0);
    async16(&Qh[t1 * 512], wqh + wo1 + k0);
    async16(&Ql[t0 * 512], wql + wo0 + k0);
    async16(&Ql[t1 * 512], wql + wo1 + k0);
    async16(&Kh[t0 * 512], wkh + wo0 + k0);
    async16(&Kh[t1 * 512], wkh + wo1 + k0);
    async16(&Kl[t0 * 512], wkl + wo0 + k0);
    async16(&Kl[t1 * 512], wkl + wo1 + k0);
    async16(&Vh[t0 * 512], wvh + wo0 + k0);
    async16(&Vh[t1 * 512], wvh + wo1 + k0);
    __syncthreads();
    bf16x8 ah0 = ld8(&Xh[t0 * 512 + lane * 8]);
    bf16x8 ah1 = ld8(&Xh[t1 * 512 + lane * 8]);
    bf16x8 al0 = ld8(&Xl[t0 * 512 + lane * 8]);
    bf16x8 al1 = ld8(&Xl[t1 * 512 + lane * 8]);
#pragma unroll
    for (int j = 0; j < 8; j++) {
      bf16x8 b;
      b = ld8(&Qh[j * 512 + lane * 8]);
      accQ[0][j] = MFMA16(ah0, b, accQ[0][j]);
      accQ[1][j] = MFMA16(ah1, b, accQ[1][j]);
      accQ[0][j] = MFMA16(al0, b, accQ[0][j]);
      accQ[1][j] = MFMA16(al1, b, accQ[1][j]);
      b = ld8(&Ql[j * 512 + lane * 8]);
      accQ[0][j] = MFMA16(ah0, b, accQ[0][j]);
      accQ[1][j] = MFMA16(ah1, b, accQ[1][j]);
      b = ld8(&Kh[j * 512 + lane * 8]);
      accK[0][j] = MFMA16(ah0, b, accK[0][j]);
      accK[1][j] = MFMA16(ah1, b, accK[1][j]);
      accK[0][j] = MFMA16(al0, b, accK[0][j]);
      accK[1][j] = MFMA16(al1, b, accK[1][j]);
      b = ld8(&Kl[j * 512 + lane * 8]);
      accK[0][j] = MFMA16(ah0, b, accK[0][j]);
      accK[1][j] = MFMA16(ah1, b, accK[1][j]);
      b = ld8(&Vh[j * 512 + lane * 8]);
      accV[0][j] = MFMA16(ah0, b, accV[0][j]);
      accV[1][j] = MFMA16(ah1, b, accV[1][j]);
    }
  }

  // Epilogue
  const int h = n0 >> 7;
  const float escQ = 512.0f;       // sqrt(2048)*sqrt(128)
  const float escK = 45.254834f;   // sqrt(2048)
#pragma unroll
  for (int i = 0; i < 2; i++) {
    int rbase = m0 + (2 * w + i) * 16 + quad * 4;
#pragma unroll
    for (int r = 0; r < 4; r++) {
      int row = rbase + r;
      int bb = row >> 11, t = row & 2047;
      size_t base = (((size_t)(bb * 16 + h)) * 2048 + (size_t)t) * 128;
#pragma unroll
      for (int j = 0; j < 4; j++) {
        int d = j * 16 + l16;  // 0..63
        float c = cosT[t * 64 + d], s = sinT[t * 64 + d];
        float s1 = sqk[h * 128 + d], s2 = sqk[h * 128 + d + 64];
        // Q
        {
          float xr = accQ[i][j][r], xi = accQ[i][j + 4][r];
          float o1 = (xr * c - xi * s) * (s1 * escQ);
          float o2 = (xr * s + xi * c) * (s2 * escQ);
          unsigned short h1 = f2bf(o1), h2 = f2bf(o2);
          qhi[base + d] = h1;
          qlo[base + d] = f2bf(o1 - bf2f(h1));
          qhi[base + d + 64] = h2;
          qlo[base + d + 64] = f2bf(o2 - bf2f(h2));
        }
        // K
        {
          float xr = accK[i][j][r], xi = accK[i][j + 4][r];
          float o1 = (xr * c - xi * s) * (s1 * escK);
          float o2 = (xr * s + xi * c) * (s2 * escK);
          unsigned short h1 = f2bf(o1), h2 = f2bf(o2);
          khi[base + d] = h1;
          klo[base + d] = f2bf(o1 - bf2f(h1));
          khi[base + d + 64] = h2;
          klo[base + d + 64] = f2bf(o2 - bf2f(h2));
        }
        // V (plain)
        vout[base + d] = f2bf(accV[i][j][r]);
        vout[base + d + 64] = f2bf(accV[i][j + 4][r]);
      }
    }
  }
}

// ---------------------------------------------------------------------------
// Plain GEMM C = A @ B^T, 128x128 tile, BK=64 (two 32-k sub-tiles per
// barrier pair -> half the barrier drains), fp32 out.
// ---------------------------------------------------------------------------
__global__ __launch_bounds__(256, 2) void gemm_o(
    const unsigned short* __restrict__ A, const unsigned short* __restrict__ B,
    float* __restrict__ outF) {
  constexpr int Kd = 2048;
  constexpr int Nd = 2048;
  const int n0 = blockIdx.x * 128, m0 = blockIdx.y * 128;
  const int tid = threadIdx.x, w = tid >> 6, lane = tid & 63;
  const int quad = lane >> 4, l16 = lane & 15;

  __shared__ __align__(16) unsigned short As[8192];  // 2 sub-tiles of 4096
  __shared__ __align__(16) unsigned short Bs[8192];

  floatx4 acc[2][8];
#pragma unroll
  for (int i = 0; i < 2; i++)
#pragma unroll
    for (int j = 0; j < 8; j++) acc[i][j] = (floatx4){0.f, 0.f, 0.f, 0.f};

  const int t0 = 2 * w, t1 = 2 * w + 1;
  const size_t ao0 = (size_t)(m0 + t0 * 16 + l16) * Kd + quad * 8;
  const size_t ao1 = (size_t)(m0 + t1 * 16 + l16) * Kd + quad * 8;
  const size_t bo0 = (size_t)(n0 + t0 * 16 + l16) * Kd + quad * 8;
  const size_t bo1 = (size_t)(n0 + t1 * 16 + l16) * Kd + quad * 8;

  for (int k0 = 0; k0 < Kd; k0 += 64) {
    __syncthreads();
    async16(&As[t0 * 512], A + ao0 + k0);
    async16(&As[t1 * 512], A + ao1 + k0);
    async16(&As[4096 + t0 * 512], A + ao0 + k0 + 32);
    async16(&As[4096 + t1 * 512], A + ao1 + k0 + 32);
    async16(&Bs[t0 * 512], B + bo0 + k0);
    async16(&Bs[t1 * 512], B + bo1 + k0);
    async16(&Bs[4096 + t0 * 512], B + bo0 + k0 + 32);
    async16(&Bs[4096 + t1 * 512], B + bo1 + k0 + 32);
    __syncthreads();
    bf16x8 a00 = ld8(&As[t0 * 512 + lane * 8]);
    bf16x8 a10 = ld8(&As[t1 * 512 + lane * 8]);
    bf16x8 a01 = ld8(&As[4096 + t0 * 512 + lane * 8]);
    bf16x8 a11 = ld8(&As[4096 + t1 * 512 + lane * 8]);
#pragma unroll
    for (int j = 0; j < 8; j++) {
      bf16x8 b0 = ld8(&Bs[j * 512 + lane * 8]);
      acc[0][j] = MFMA16(a00, b0, acc[0][j]);
      acc[1][j] = MFMA16(a10, b0, acc[1][j]);
      bf16x8 b1 = ld8(&Bs[4096 + j * 512 + lane * 8]);
      acc[0][j] = MFMA16(a01, b1, acc[0][j]);
      acc[1][j] = MFMA16(a11, b1, acc[1][j]);
    }
  }

#pragma unroll
  for (int i = 0; i < 2; i++) {
    int rbase = m0 + (2 * w + i) * 16 + quad * 4;
#pragma unroll
    for (int j = 0; j < 8; j++) {
      int col = n0 + j * 16 + l16;
#pragma unroll
      for (int r = 0; r < 4; r++)
        outF[(size_t)(rbase + r) * Nd + col] = acc[i][j][r];
    }
  }
}

// ---------------------------------------------------------------------------
// transpose V: [BH][T][HD] -> [BH][HD][T] (bf16)
// ---------------------------------------------------------------------------
__global__ __launch_bounds__(256) void transpose_v(
    const unsigned short* __restrict__ v, unsigned short* __restrict__ vt) {
  __shared__ unsigned short tile[32][33];
  int t0 = blockIdx.x * 32, d0 = blockIdx.y * 32, bh = blockIdx.z;
  int tx = threadIdx.x & 31, ty = threadIdx.x >> 5;
  for (int r = ty; r < 32; r += 8)
    tile[r][tx] = v[((size_t)bh * 2048 + t0 + r) * 128 + d0 + tx];
  __syncthreads();
  for (int r = ty; r < 32; r += 8)
    vt[((size_t)bh * 128 + d0 + r) * 2048 + t0 + tx] = tile[tx][r];
}

// ---------------------------------------------------------------------------
// flash attention: block = (q-tile of 128 rows, bh). 4 waves x 32 rows.
// K-tiles of 64, QK^T 3-pass split-bf16, online softmax fp32, PV bf16.
// ---------------------------------------------------------------------------
__global__ __launch_bounds__(256, 2) void flash_attn(
    const unsigned short* __restrict__ qhi, const unsigned short* __restrict__ qlo,
    const unsigned short* __restrict__ khi, const unsigned short* __restrict__ klo,
    const unsigned short* __restrict__ vtp, unsigned short* __restrict__ aout) {
  constexpr int T = 2048, HD = 128;
  const int qt = blockIdx.x, bh = blockIdx.y;
  const int q0 = qt * 128;
  const int tid = threadIdx.x, w = tid >> 6, lane = tid & 63;
  const int quad = lane >> 4, l16 = lane & 15;

  __shared__ __align__(16) unsigned short Khi[8192];   // 64 x 128, granule layout
  __shared__ __align__(16) unsigned short Klo[8192];
  __shared__ __align__(16) unsigned short Vt[8192];    // 128 x 64, granule layout
  __shared__ __align__(16) unsigned short Pb[4][16 * 72];  // per-wave, padded

  const size_t qkbase = (size_t)bh * T * HD;

  bf16x8 qh[2][4], ql[2][4];
#pragma unroll
  for (int i = 0; i < 2; i++)
#pragma unroll
    for (int s = 0; s < 4; s++) {
      size_t off = qkbase + (size_t)(q0 + w * 32 + i * 16 + l16) * HD + s * 32 + quad * 8;
      qh[i][s] = *(const bf16x8*)(qhi + off);
      ql[i][s] = *(const bf16x8*)(qlo + off);
    }

  floatx4 o[2][8];
#pragma unroll
  for (int i = 0; i < 2; i++)
#pragma unroll
    for (int dt = 0; dt < 8; dt++) o[i][dt] = (floatx4){0.f, 0.f, 0.f, 0.f};
  float mrow[2][4], lrow[2][4];
#pragma unroll
  for (int i = 0; i < 2; i++)
#pragma unroll
    for (int r = 0; r < 4; r++) { mrow[i][r] = -3e38f; lrow[i][r] = 0.f; }

  const int ntiles = q0 / 64 + 2;
  for (int kt = 0; kt < ntiles; ++kt) {
    const int s0 = kt * 64;
    __syncthreads();
    for (int c = w; c < 16; c += 4) {
      int tt = c >> 2, ss = c & 3;
      size_t go = qkbase + (size_t)(s0 + tt * 16 + l16) * HD + ss * 32 + quad * 8;
      async16(&Khi[c * 512], khi + go);
      async16(&Klo[c * 512], klo + go);
      int dt = c >> 1, vs = c & 1;
      size_t vo = (size_t)bh * HD * T + (size_t)(dt * 16 + l16) * T + s0 + vs * 32 + quad * 8;
      async16(&Vt[c * 512], vtp + vo);
    }
    __syncthreads();

    floatx4 S[2][4];
#pragma unroll
    for (int i = 0; i < 2; i++)
#pragma unroll
      for (int j = 0; j < 4; j++) S[i][j] = (floatx4){0.f, 0.f, 0.f, 0.f};

#pragma unroll
    for (int s = 0; s < 4; s++) {
#pragma unroll
      for (int j = 0; j < 4; j++) {
        bf16x8 kh = ld8(&Khi[(j * 4 + s) * 512 + lane * 8]);
        bf16x8 kl = ld8(&Klo[(j * 4 + s) * 512 + lane * 8]);
        S[0][j] = MFMA16(qh[0][s], kh, S[0][j]);
        S[1][j] = MFMA16(qh[1][s], kh, S[1][j]);
        S[0][j] = MFMA16(ql[0][s], kh, S[0][j]);
        S[1][j] = MFMA16(ql[1][s], kh, S[1][j]);
        S[0][j] = MFMA16(qh[0][s], kl, S[0][j]);
        S[1][j] = MFMA16(qh[1][s], kl, S[1][j]);
      }
    }

    if (s0 + 63 > q0) {  // causal mask (only near-diagonal tiles)
#pragma unroll
      for (int i = 0; i < 2; i++) {
        int rb = q0 + w * 32 + i * 16 + quad * 4;
#pragma unroll
        for (int j = 0; j < 4; j++) {
          int cg = s0 + j * 16 + l16;
#pragma unroll
          for (int r = 0; r < 4; r++)
            if (cg > rb + r) S[i][j][r] = -3e38f;
        }
      }
    }

    bf16x8 pf[2][2];
#pragma unroll
    for (int i = 0; i < 2; i++) {
#pragma unroll
      for (int r = 0; r < 4; r++) {
        float mx = fmaxf(fmaxf(S[i][0][r], S[i][1][r]), fmaxf(S[i][2][r], S[i][3][r]));
#pragma unroll
        for (int d = 1; d < 16; d <<= 1) mx = fmaxf(mx, __shfl_xor(mx, d, 64));
        float mnew = fmaxf(mrow[i][r], mx);
        float al = __expf(mrow[i][r] - mnew);
        mrow[i][r] = mnew;
        float sum = 0.f;
#pragma unroll
        for (int j = 0; j < 4; j++) {
          float p = __expf(S[i][j][r] - mnew);
          S[i][j][r] = p;
          sum += p;
        }
#pragma unroll
        for (int d = 1; d < 16; d <<= 1) sum += __shfl_xor(sum, d, 64);
        lrow[i][r] = lrow[i][r] * al + sum;
#pragma unroll
        for (int dt = 0; dt < 8; dt++) o[i][dt][r] *= al;
      }
      // P -> LDS (A-fragment transform); per-wave buffer, DS ops in-order per wave
#pragma unroll
      for (int r = 0; r < 4; r++)
#pragma unroll
        for (int j = 0; j < 4; j++)
          Pb[w][(quad * 4 + r) * 72 + j * 16 + l16] = f2bf(S[i][j][r]);
      pf[i][0] = ld8(&Pb[w][l16 * 72 + quad * 8]);
      pf[i][1] = ld8(&Pb[w][l16 * 72 + 32 + quad * 8]);
    }

#pragma unroll
    for (int dt = 0; dt < 8; dt++) {
#pragma unroll
      for (int s = 0; s < 2; s++) {
        bf16x8 vf = ld8(&Vt[(dt * 2 + s) * 512 + lane * 8]);
        o[0][dt] = MFMA16(pf[0][s], vf, o[0][dt]);
        o[1][dt] = MFMA16(pf[1][s], vf, o[1][dt]);
      }
    }
  }

  const int b = bh >> 4, h = bh & 15;
#pragma unroll
  for (int i = 0; i < 2; i++) {
#pragma unroll
    for (int r = 0; r < 4; r++) {
      int trow = q0 + w * 32 + i * 16 + quad * 4 + r;
      float linv = 1.0f / lrow[i][r];
      size_t base = ((size_t)(b * T + trow)) * 2048 + h * 128;
#pragma unroll
      for (int dt = 0; dt < 8; dt++)
        aout[base + dt * 16 + l16] = f2bf(o[i][dt][r] * linv);
    }
  }
}

// ---------------------------------------------------------------------------
// per-row L2 normalize: out = y / max(||y||, 1e-12)
// ---------------------------------------------------------------------------
__global__ __launch_bounds__(256) void rownorm(const float* __restrict__ y,
                                               float* __restrict__ out) {
  int row = blockIdx.x;
  const float4* yr = (const float4*)(y + (size_t)row * 2048);
  float4* od = (float4*)(out + (size_t)row * 2048);
  int t = threadIdx.x;
  float4 v0 = yr[t], v1 = yr[t + 256];
  float ss = v0.x * v0.x + v0.y * v0.y + v0.z * v0.z + v0.w * v0.w +
             v1.x * v1.x + v1.y * v1.y + v1.z * v1.z + v1.w * v1.w;
#pragma unroll
  for (int d = 1; d < 64; d <<= 1) ss += __shfl_xor(ss, d, 64);
  __shared__ float red[4];
  if ((t & 63) == 0) red[t >> 6] = ss;
  __syncthreads();
  float tot = red[0] + red[1] + red[2] + red[3];
  float inv = 1.0f / fmaxf(sqrtf(tot), 1e-12f);
  v0.x *= inv; v0.y *= inv; v0.z *= inv; v0.w *= inv;
  v1.x *= inv; v1.y *= inv; v1.z *= inv; v1.w *= inv;
  od[t] = v0;
  od[t + 256] = v1;
}

// ---------------------------------------------------------------------------
extern "C" void kernel_launch(void* const* d_in, const int* in_sizes, int n_in,
                              void* d_out, int out_size, void* d_ws, size_t ws_size,
                              hipStream_t stream) {
  (void)in_sizes; (void)n_in; (void)out_size; (void)ws_size;
  const float* x   = (const float*)d_in[0];
  const float* Wq  = (const float*)d_in[1];
  const float* Wk  = (const float*)d_in[2];
  const float* Wv  = (const float*)d_in[3];
  const float* Wo  = (const float*)d_in[4];
  const float* sqk = (const float*)d_in[5];
  char* ws = (char*)d_ws;

  constexpr size_t NX = 8388608;   // 2*2048*2048
  constexpr size_t NW = 4194304;   // 2048*2048
  constexpr size_t SZX = NX * 2;   // bf16 bytes
  constexpr size_t SZW = NW * 2;

  size_t o_xhi  = 0;
  size_t o_xlo  = o_xhi + SZX;
  size_t o_wqhi = o_xlo + SZX;
  size_t o_wqlo = o_wqhi + SZW;
  size_t o_wkhi = o_wqlo + SZW;
  size_t o_wklo = o_wkhi + SZW;
  size_t o_wvhi = o_wklo + SZW;
  size_t o_wohi = o_wvhi + SZW;
  size_t o_qhi  = o_wohi + SZW;
  size_t o_qlo  = o_qhi + SZX;
  size_t o_khi  = o_qlo + SZX;
  size_t o_klo  = o_khi + SZX;
  size_t o_v    = o_klo + SZX;
  size_t o_vt   = o_v + SZX;
  size_t o_cos  = o_vt + SZX;
  size_t o_sin  = o_cos + 2048 * 64 * 4;
  // aliases (lifetimes disjoint):
  size_t o_y    = o_xhi;   // fp32 y over x_hi+x_lo (x dead after projections)
  size_t o_aout = o_wqhi;  // attn-out over wq_hi+wq_lo (dead after QKV proj)

  unsigned short* xhi  = (unsigned short*)(ws + o_xhi);
  unsigned short* xlo  = (unsigned short*)(ws + o_xlo);
  unsigned short* wqhi = (unsigned short*)(ws + o_wqhi);
  unsigned short* wqlo = (unsigned short*)(ws + o_wqlo);
  unsigned short* wkhi = (unsigned short*)(ws + o_wkhi);
  unsigned short* wklo = (unsigned short*)(ws + o_wklo);
  unsigned short* wvhi = (unsigned short*)(ws + o_wvhi);
  unsigned short* wohi = (unsigned short*)(ws + o_wohi);
  unsigned short* qhi  = (unsigned short*)(ws + o_qhi);
  unsigned short* qlo  = (unsigned short*)(ws + o_qlo);
  unsigned short* khi  = (unsigned short*)(ws + o_khi);
  unsigned short* klo  = (unsigned short*)(ws + o_klo);
  unsigned short* v    = (unsigned short*)(ws + o_v);
  unsigned short* vt   = (unsigned short*)(ws + o_vt);
  float* cosT = (float*)(ws + o_cos);
  float* sinT = (float*)(ws + o_sin);
  float* y    = (float*)(ws + o_y);
  unsigned short* aout = (unsigned short*)(ws + o_aout);

  // prep
  split_kernel<<<(int)(NX / 4 / 256), 256, 0, stream>>>((const float4*)x, (ushort4*)xhi, (ushort4*)xlo, (int)(NX / 4));
  split_kernel<<<(int)(NW / 4 / 256), 256, 0, stream>>>((const float4*)Wq, (ushort4*)wqhi, (ushort4*)wqlo, (int)(NW / 4));
  split_kernel<<<(int)(NW / 4 / 256), 256, 0, stream>>>((const float4*)Wk, (ushort4*)wkhi, (ushort4*)wklo, (int)(NW / 4));
  split_kernel<<<(int)(NW / 4 / 256), 256, 0, stream>>>((const float4*)Wv, (ushort4*)wvhi, (ushort4*)nullptr, (int)(NW / 4));
  split_kernel<<<(int)(NW / 4 / 256), 256, 0, stream>>>((const float4*)Wo, (ushort4*)wohi, (ushort4*)nullptr, (int)(NW / 4));
  rope_tables<<<512, 256, 0, stream>>>(cosT, sinT);

  // Fused Q/K/V projection (+RoPE/scale/split epilogue)
  gemm_qkv<<<dim3(16, 32), 256, 0, stream>>>(xhi, xlo, wqhi, wqlo, wkhi, wklo, wvhi,
                                             cosT, sinT, sqk,
                                             qhi, qlo, khi, klo, v);
  transpose_v<<<dim3(64, 4, 32), 256, 0, stream>>>(v, vt);

  flash_attn<<<dim3(16, 32), 256, 0, stream>>>(qhi, qlo, khi, klo, vt, aout);

  // y = aout @ Wo^T (fp32 out)
  gemm_o<<<dim3(16, 32), 256, 0, stream>>>(aout, wohi, y);
  rownorm<<<4096, 256, 0, stream>>>(y, (float*)d_out);
}